// Round 10
// baseline (43.636 us; speedup 1.0000x reference)
//
#include <hip/hip_runtime.h>
#include <math.h>

// NonLinearReadoutBlock, round 10: all-MFMA datapath using ONLY the verified
// 16x16x32 bf16 intrinsic. GEMM1 swapped (A=W1 frag, B=x frag; loads identical
// to r8) so D1[o=4q+v][row=rw]: silu/gating lane-local. Layer 2 as ONE K=32
// GEMM pair: k=8q+j slots j<4 = z-matrix-A[o=4q+j], j>=4 = z-matrix-B -- the
// exact 4 values/lane GEMM1 produced, zero cross-lane traffic. MFMA#1 covers
// {z_s, z_g0}, MFMA#2 {z_g1, z_g2}; resident A2 frags encode W2s/W2v with
// zeros in dead (m,k) slots; b2 bias pre-folded (x4) into the accumulator.
// No LDS, no waits, no barriers. Keeps r8's tile pipeline + peeled tail.

typedef short  bf16x8 __attribute__((ext_vector_type(8)));
typedef int    i32x4  __attribute__((ext_vector_type(4)));
typedef float  f32x4  __attribute__((ext_vector_type(4)));

static __device__ __forceinline__ short f2bf(float f) {
    union { float f; unsigned u; } v; v.f = f;
    return (short)((v.u + 0x8000u) >> 16);
}
static __device__ __forceinline__ unsigned cvtpk(float lo, float hi) {
    unsigned r;
    asm("v_cvt_pk_bf16_f32 %0, %1, %2" : "=v"(r) : "v"(lo), "v"(hi));
    return r;   // {lo16: bf16(lo), hi16: bf16(hi)}
}

#define BLOCK 256
#define MFMA32(a, b, c) __builtin_amdgcn_mfma_f32_16x16x32_bf16(a, b, c, 0, 0, 0)

__global__ __launch_bounds__(BLOCK, 2) void nlrb_kernel(
    const float* __restrict__ x,
    const float* __restrict__ W1s,   // (128,32)
    const float* __restrict__ W1v,   // (128,16)
    const float* __restrict__ b1s,   // (32)
    const float* __restrict__ W2s,   // (16,10)
    const float* __restrict__ W2v,   // (16)
    const float* __restrict__ b2s,   // (10)
    float* __restrict__ out,         // (N,13)
    int N)
{
    const int tid  = threadIdx.x;
    const int wave = tid >> 6;
    const int lane = tid & 63;
    const int q    = lane >> 4;   // k-chunk group
    const int rw   = lane & 15;   // x data-row within tile (and A2's m index)
    const float inv1 = 0.08838834764831843f;  // 1/sqrt(128)

    // ---- one-time: resident W1 fragments (used as A operand of GEMM1) ----
    bf16x8 bS0[4], bS1[4], bV[4];
    #pragma unroll
    for (int kb = 0; kb < 4; ++kb) {
        #pragma unroll
        for (int j = 0; j < 8; ++j) {
            const int k = kb * 32 + q * 8 + j;
            bS0[kb][j] = f2bf(W1s[k * 32 + rw]);
            bS1[kb][j] = f2bf(W1s[k * 32 + 16 + rw]);
            bV [kb][j] = f2bf(W1v[k * 16 + rw]);
        }
    }

    // ---- per-lane layer-1 biases, indexed by hidden o = 4q+v ----
    float b1sv[4], b1gv[4], b2v4[4];
    #pragma unroll
    for (int v = 0; v < 4; ++v) {
        const int j = q * 4 + v;
        b1sv[v] = b1s[j];
        b1gv[v] = b1s[16 + j];
        b2v4[v] = (j < 10) ? b2s[j] * 4.0f : 0.0f;   // pre-scaled by 1/0.25
    }

    // ---- resident layer-2 A fragments: A2[m=e=rw][k=8q+j] ----
    // MFMA#1: j<4 -> W2s column e (pairs with z_s); j>=4 -> W2v row (e==10,
    // pairs with z_g0). MFMA#2: j<4 -> e==11 (z_g1); j>=4 -> e==12 (z_g2).
    bf16x8 a2A, a2B;
    #pragma unroll
    for (int j = 0; j < 8; ++j) {
        const int o = q * 4 + (j & 3);
        a2A[j] = f2bf((j < 4) ? ((rw < 10)  ? W2s[o * 10 + rw] : 0.0f)
                              : ((rw == 10) ? W2v[o] : 0.0f));
        a2B[j] = f2bf((j < 4) ? ((rw == 11) ? W2v[o] : 0.0f)
                              : ((rw == 12) ? W2v[o] : 0.0f));
    }

    const int NT = N >> 4;                 // 6250 tiles
    const int wstride = gridDim.x << 2;
    const int wt0 = (blockIdx.x << 2) + wave;

    float4 LS[4][2], LV[4][6];

#define ISSUE_S(kb, xp)                                                      \
    do {                                                                     \
        LS[kb][0] = *(const float4*)((xp) + (kb) * 32 + q * 8);              \
        LS[kb][1] = *(const float4*)((xp) + (kb) * 32 + q * 8 + 4);          \
    } while (0)
#define ISSUE_V(kb, xp)                                                      \
    do {                                                                     \
        _Pragma("unroll")                                                    \
        for (int qq = 0; qq < 6; ++qq)                                       \
            LV[kb][qq] = *(const float4*)((xp) + 128 + (kb) * 96 + q * 24 + qq * 4); \
    } while (0)

#define TILE_BODY(PF)                                                        \
    do {                                                                     \
        f32x4 accS0 = {0.f,0.f,0.f,0.f}, accS1 = {0.f,0.f,0.f,0.f};          \
        f32x4 accV0 = {0.f,0.f,0.f,0.f}, accV1 = {0.f,0.f,0.f,0.f};          \
        f32x4 accV2 = {0.f,0.f,0.f,0.f};                                     \
        /* GEMM1, A=W frag, B=x frag: D1[o=4q+v][row=rw] */                  \
        _Pragma("unroll")                                                    \
        for (int kb = 0; kb < 4; ++kb) {                                     \
            i32x4 wv;                                                        \
            wv[0] = (int)cvtpk(LS[kb][0].x, LS[kb][0].y);                    \
            wv[1] = (int)cvtpk(LS[kb][0].z, LS[kb][0].w);                    \
            wv[2] = (int)cvtpk(LS[kb][1].x, LS[kb][1].y);                    \
            wv[3] = (int)cvtpk(LS[kb][1].z, LS[kb][1].w);                    \
            if (PF) ISSUE_S(kb, xq);                                         \
            const bf16x8 a = __builtin_bit_cast(bf16x8, wv);                 \
            accS0 = MFMA32(bS0[kb], a, accS0);                               \
            accS1 = MFMA32(bS1[kb], a, accS1);                               \
        }                                                                    \
        _Pragma("unroll")                                                    \
        for (int kb = 0; kb < 4; ++kb) {                                     \
            unsigned p[12];                                                  \
            _Pragma("unroll")                                                \
            for (int qq = 0; qq < 6; ++qq) {                                 \
                p[2*qq]   = cvtpk(LV[kb][qq].x, LV[kb][qq].y);               \
                p[2*qq+1] = cvtpk(LV[kb][qq].z, LV[kb][qq].w);               \
            }                                                                \
            if (PF) ISSUE_V(kb, xq);                                         \
            i32x4 w0, w1, w2;                                                \
            _Pragma("unroll")                                                \
            for (int w = 0; w < 4; ++w) {                                    \
                w0[w] = (int)__builtin_amdgcn_perm(p[3*w+1], p[3*w],   0x07060100u); \
                w1[w] = (int)__builtin_amdgcn_perm(p[3*w+2], p[3*w],   0x05040302u); \
                w2[w] = (int)__builtin_amdgcn_perm(p[3*w+2], p[3*w+1], 0x07060100u); \
            }                                                                \
            const bf16x8 a0 = __builtin_bit_cast(bf16x8, w0);                \
            const bf16x8 a1 = __builtin_bit_cast(bf16x8, w1);                \
            const bf16x8 a2 = __builtin_bit_cast(bf16x8, w2);                \
            accV0 = MFMA32(bV[kb], a0, accV0);                               \
            accV1 = MFMA32(bV[kb], a1, accV1);                               \
            accV2 = MFMA32(bV[kb], a2, accV2);                               \
        }                                                                    \
        /* epilogue: lane-local silu/gate -> B2 frags -> 2x MFMA layer 2 */  \
        float sv[4], g0[4], g1[4], g2[4];                                    \
        _Pragma("unroll")                                                    \
        for (int v = 0; v < 4; ++v) {                                        \
            const float hs = fmaf(accS0[v], inv1, b1sv[v]);                  \
            const float hg = fmaf(accS1[v], inv1, b1gv[v]);                  \
            const float s  = hs / (1.f + __expf(-hs));                       \
            const float g  = hg / (1.f + __expf(-hg));                       \
            const float gm = g * inv1;                                       \
            sv[v] = s;                                                       \
            g0[v] = gm * accV0[v];                                           \
            g1[v] = gm * accV1[v];                                           \
            g2[v] = gm * accV2[v];                                           \
        }                                                                    \
        i32x4 bA, bB;                                                        \
        bA[0] = (int)cvtpk(sv[0], sv[1]); bA[1] = (int)cvtpk(sv[2], sv[3]);  \
        bA[2] = (int)cvtpk(g0[0], g0[1]); bA[3] = (int)cvtpk(g0[2], g0[3]);  \
        bB[0] = (int)cvtpk(g1[0], g1[1]); bB[1] = (int)cvtpk(g1[2], g1[3]);  \
        bB[2] = (int)cvtpk(g2[0], g2[1]); bB[3] = (int)cvtpk(g2[2], g2[3]);  \
        f32x4 acc2 = {b2v4[0], b2v4[1], b2v4[2], b2v4[3]};                   \
        acc2 = MFMA32(a2A, __builtin_bit_cast(bf16x8, bA), acc2);            \
        acc2 = MFMA32(a2B, __builtin_bit_cast(bf16x8, bB), acc2);            \
        _Pragma("unroll")                                                    \
        for (int v = 0; v < 4; ++v) {                                        \
            const int e = (q << 2) + v;                                      \
            if (e < 13)                                                      \
                out[(size_t)((base) + rw) * 13 + e] = acc2[v] * 0.25f;       \
        }                                                                    \
    } while (0)

    // ---- prologue: burst all 32 loads of tile wt0 ----
    if (wt0 < NT) {
        const float* xp = x + (size_t)((wt0 << 4) + rw) * 512;
        #pragma unroll
        for (int kb = 0; kb < 4; ++kb) { ISSUE_S(kb, xp); ISSUE_V(kb, xp); }
    }

    int wt = wt0;
    for (; wt + wstride < NT; wt += wstride) {
        const int base = wt << 4;
        const float* xq = x + (size_t)(((wt + wstride) << 4) + rw) * 512;
        TILE_BODY(1);
    }
    if (wt < NT) {
        const int base = wt << 4;
        const float* xq = nullptr; (void)xq;
        TILE_BODY(0);
    }
#undef ISSUE_S
#undef ISSUE_V
#undef TILE_BODY
}

extern "C" void kernel_launch(void* const* d_in, const int* in_sizes, int n_in,
                              void* d_out, int out_size, void* d_ws, size_t ws_size,
                              hipStream_t stream) {
    const float* x   = (const float*)d_in[0];
    const float* W1s = (const float*)d_in[1];
    const float* W1v = (const float*)d_in[2];
    const float* b1s = (const float*)d_in[3];
    const float* W2s = (const float*)d_in[4];
    const float* W2v = (const float*)d_in[5];
    const float* b2s = (const float*)d_in[6];
    float* outp = (float*)d_out;
    const int N = in_sizes[0] / 512;   // 100000
    nlrb_kernel<<<dim3(512), dim3(BLOCK), 0, stream>>>(
        x, W1s, W1v, b1s, W2s, W2v, b2s, outp, N);
}

// Round 11
// 40.453 us; speedup vs baseline: 1.0787x; 1.0787x over previous
//
#include <hip/hip_runtime.h>
#include <math.h>

// NonLinearReadoutBlock, round 11 = round 8 verbatim (the measured champion,
// 40.2 us). r5's pipelined structure with the redundant-fetch bug removed.
// Main loop prefetches next tile unconditionally into the same load registers
// right after each granule's conversion; the final tile is PEELED into a
// no-prefetch body. Resident B fragments in VGPRs, cvt_pk+v_perm conversion,
// wave-private LDS for layer 2 only. launch_bounds(256,2), grid 512.

typedef short  bf16x8 __attribute__((ext_vector_type(8)));
typedef int    i32x4  __attribute__((ext_vector_type(4)));
typedef float  f32x4  __attribute__((ext_vector_type(4)));

static __device__ __forceinline__ short f2bf(float f) {
    union { float f; unsigned u; } v; v.f = f;
    return (short)((v.u + 0x8000u) >> 16);
}
static __device__ __forceinline__ unsigned cvtpk(float lo, float hi) {
    unsigned r;
    asm("v_cvt_pk_bf16_f32 %0, %1, %2" : "=v"(r) : "v"(lo), "v"(hi));
    return r;   // {lo16: bf16(lo), hi16: bf16(hi)}
}

#define BLOCK 256

__global__ __launch_bounds__(BLOCK, 2) void nlrb_kernel(
    const float* __restrict__ x,
    const float* __restrict__ W1s,   // (128,32)
    const float* __restrict__ W1v,   // (128,16)
    const float* __restrict__ b1s,   // (32)
    const float* __restrict__ W2s,   // (16,10)
    const float* __restrict__ W2v,   // (16)
    const float* __restrict__ b2s,   // (10)
    float* __restrict__ out,         // (N,13)
    int N)
{
    __shared__ float sred[4][16][68];   // wave-private layer-2 scratch

    const int tid  = threadIdx.x;
    const int wave = tid >> 6;
    const int lane = tid & 63;
    const int mq   = lane >> 4;
    const int o    = lane & 15;
    const float inv1 = 0.08838834764831843f;  // 1/sqrt(128)

    // ---- one-time: resident B fragments (bf16, 48 VGPR) ----
    bf16x8 bS0[4], bS1[4], bV[4];
    #pragma unroll
    for (int kb = 0; kb < 4; ++kb) {
        #pragma unroll
        for (int j = 0; j < 8; ++j) {
            const int k = kb * 32 + mq * 8 + j;
            bS0[kb][j] = f2bf(W1s[k * 32 + o]);
            bS1[kb][j] = f2bf(W1s[k * 32 + 16 + o]);
            bV [kb][j] = f2bf(W1v[k * 16 + o]);
        }
    }
    // ---- one-time: layer-2 weights (fp32, per-lane) ----
    float wcr[16];
    #pragma unroll
    for (int j = 0; j < 16; ++j)
        wcr[j] = (o < 10) ? W2s[j * 10 + o] : W2v[j];
    const float b2e = (o < 10) ? b2s[o] : 0.0f;
    const float b1a = b1s[o];
    const float b1b = b1s[16 + o];

    const int NT = N >> 4;                 // 6250 tiles
    const int wstride = gridDim.x << 2;
    const int wt0 = (blockIdx.x << 2) + wave;

    float4 LS[4][2], LV[4][6];

// issue loads of one kb-granule for tile at row-pointer xp
#define ISSUE_S(kb, xp)                                                      \
    do {                                                                     \
        LS[kb][0] = *(const float4*)((xp) + (kb) * 32 + mq * 8);             \
        LS[kb][1] = *(const float4*)((xp) + (kb) * 32 + mq * 8 + 4);         \
    } while (0)
#define ISSUE_V(kb, xp)                                                      \
    do {                                                                     \
        _Pragma("unroll")                                                    \
        for (int q = 0; q < 6; ++q)                                          \
            LV[kb][q] = *(const float4*)((xp) + 128 + (kb) * 96 + mq * 24 + q * 4); \
    } while (0)

// One full tile body. PF: 1 = prefetch next tile (pointer xq) into L regs.
#define TILE_BODY(PF)                                                        \
    do {                                                                     \
        f32x4 accS0 = {0.f,0.f,0.f,0.f}, accS1 = {0.f,0.f,0.f,0.f};          \
        f32x4 accV0 = {0.f,0.f,0.f,0.f}, accV1 = {0.f,0.f,0.f,0.f};          \
        f32x4 accV2 = {0.f,0.f,0.f,0.f};                                     \
        /* S phase: convert -> reissue(next tile) -> MFMA, per kb */         \
        _Pragma("unroll")                                                    \
        for (int kb = 0; kb < 4; ++kb) {                                     \
            i32x4 wv;                                                        \
            wv[0] = (int)cvtpk(LS[kb][0].x, LS[kb][0].y);                    \
            wv[1] = (int)cvtpk(LS[kb][0].z, LS[kb][0].w);                    \
            wv[2] = (int)cvtpk(LS[kb][1].x, LS[kb][1].y);                    \
            wv[3] = (int)cvtpk(LS[kb][1].z, LS[kb][1].w);                    \
            if (PF) ISSUE_S(kb, xq);                                         \
            const bf16x8 a = __builtin_bit_cast(bf16x8, wv);                 \
            accS0 = __builtin_amdgcn_mfma_f32_16x16x32_bf16(a, bS0[kb], accS0, 0, 0, 0); \
            accS1 = __builtin_amdgcn_mfma_f32_16x16x32_bf16(a, bS1[kb], accS1, 0, 0, 0); \
        }                                                                    \
        /* V phase: convert + stride-3 de-interleave -> reissue -> MFMA */   \
        _Pragma("unroll")                                                    \
        for (int kb = 0; kb < 4; ++kb) {                                     \
            unsigned p[12];                                                  \
            _Pragma("unroll")                                                \
            for (int q = 0; q < 6; ++q) {                                    \
                p[2*q]   = cvtpk(LV[kb][q].x, LV[kb][q].y);                  \
                p[2*q+1] = cvtpk(LV[kb][q].z, LV[kb][q].w);                  \
            }                                                                \
            if (PF) ISSUE_V(kb, xq);                                         \
            i32x4 w0, w1, w2;                                                \
            _Pragma("unroll")                                                \
            for (int w = 0; w < 4; ++w) {                                    \
                w0[w] = (int)__builtin_amdgcn_perm(p[3*w+1], p[3*w],   0x07060100u); \
                w1[w] = (int)__builtin_amdgcn_perm(p[3*w+2], p[3*w],   0x05040302u); \
                w2[w] = (int)__builtin_amdgcn_perm(p[3*w+2], p[3*w+1], 0x07060100u); \
            }                                                                \
            const bf16x8 a0 = __builtin_bit_cast(bf16x8, w0);                \
            const bf16x8 a1 = __builtin_bit_cast(bf16x8, w1);                \
            const bf16x8 a2 = __builtin_bit_cast(bf16x8, w2);                \
            accV0 = __builtin_amdgcn_mfma_f32_16x16x32_bf16(a0, bV[kb], accV0, 0, 0, 0); \
            accV1 = __builtin_amdgcn_mfma_f32_16x16x32_bf16(a1, bV[kb], accV1, 0, 0, 0); \
            accV2 = __builtin_amdgcn_mfma_f32_16x16x32_bf16(a2, bV[kb], accV2, 0, 0, 0); \
        }                                                                    \
        /* epilogue: lane-local silu + gating -> sred */                     \
        _Pragma("unroll")                                                    \
        for (int v = 0; v < 4; ++v) {                                        \
            const float hs = fmaf(accS0[v], inv1, b1a);                      \
            const float hg = fmaf(accS1[v], inv1, b1b);                      \
            const float s  = hs / (1.f + __expf(-hs));                       \
            const float g  = hg / (1.f + __expf(-hg));                       \
            const float gm = g * inv1;                                       \
            const int  r   = mq * 4 + v;                                     \
            sred[wave][r][o]      = s;                                       \
            sred[wave][r][16 + o] = gm * accV0[v];                           \
            sred[wave][r][32 + o] = gm * accV1[v];                           \
            sred[wave][r][48 + o] = gm * accV2[v];                           \
        }                                                                    \
        asm volatile("s_waitcnt lgkmcnt(0)" ::: "memory");                   \
        /* layer 2: lane o<13, dot-16 for rows mq, mq+4, mq+8, mq+12 */      \
        _Pragma("unroll")                                                    \
        for (int w = 0; w < 4; ++w) {                                        \
            const int r = (w << 2) + mq;                                     \
            if (o < 13) {                                                    \
                const int slot = (o < 10) ? 0 : (o - 9);                     \
                const float* sp = &sred[wave][r][slot * 16];                 \
                float sum = 0.f;                                             \
                _Pragma("unroll")                                            \
                for (int q = 0; q < 4; ++q) {                                \
                    const float4 pv = *(const float4*)(sp + q * 4);          \
                    sum = fmaf(pv.x, wcr[q * 4 + 0], sum);                   \
                    sum = fmaf(pv.y, wcr[q * 4 + 1], sum);                   \
                    sum = fmaf(pv.z, wcr[q * 4 + 2], sum);                   \
                    sum = fmaf(pv.w, wcr[q * 4 + 3], sum);                   \
                }                                                            \
                out[(size_t)(base + r) * 13 + o] = fmaf(sum, 0.25f, b2e);    \
            }                                                                \
        }                                                                    \
        asm volatile("s_waitcnt lgkmcnt(0)" ::: "memory");                   \
    } while (0)

    // ---- prologue: burst all 32 loads of tile wt0 ----
    if (wt0 < NT) {
        const float* xp = x + (size_t)((wt0 << 4) + o) * 512;
        #pragma unroll
        for (int kb = 0; kb < 4; ++kb) { ISSUE_S(kb, xp); ISSUE_V(kb, xp); }
    }

    int wt = wt0;
    // ---- main loop: every iteration has a valid next tile to prefetch ----
    for (; wt + wstride < NT; wt += wstride) {
        const int base = wt << 4;
        const float* xq = x + (size_t)(((wt + wstride) << 4) + o) * 512;
        TILE_BODY(1);
    }
    // ---- peeled final tile: no prefetch, no redundant fetch ----
    if (wt < NT) {
        const int base = wt << 4;
        const float* xq = nullptr; (void)xq;
        TILE_BODY(0);
    }
#undef ISSUE_S
#undef ISSUE_V
#undef TILE_BODY
}

extern "C" void kernel_launch(void* const* d_in, const int* in_sizes, int n_in,
                              void* d_out, int out_size, void* d_ws, size_t ws_size,
                              hipStream_t stream) {
    const float* x   = (const float*)d_in[0];
    const float* W1s = (const float*)d_in[1];
    const float* W1v = (const float*)d_in[2];
    const float* b1s = (const float*)d_in[3];
    const float* W2s = (const float*)d_in[4];
    const float* W2v = (const float*)d_in[5];
    const float* b2s = (const float*)d_in[6];
    float* outp = (float*)d_out;
    const int N = in_sizes[0] / 512;   // 100000
    nlrb_kernel<<<dim3(512), dim3(BLOCK), 0, stream>>>(
        x, W1s, W1v, b1s, W2s, W2v, b2s, outp, N);
}